// Round 5
// baseline (145.186 us; speedup 1.0000x reference)
//
#include <hip/hip_runtime.h>

typedef __bf16 bf16_t;
typedef bf16_t bf16x8 __attribute__((ext_vector_type(8)));
typedef float  f32x4  __attribute__((ext_vector_type(4)));

#define GAS __attribute__((address_space(1)))
#define LAS __attribute__((address_space(3)))

static constexpr int Nn = 8, Cc = 512, Hi = 32, Wi = 32, Oo = 512;
static constexpr int HO = 28, WO = 28;
static constexpr int M_ROWS = Nn * Hi * Wi;  // 8192

__device__ __forceinline__ float bf2f(unsigned short u) {
  union { unsigned int i; float f; } v; v.i = ((unsigned int)u) << 16; return v.f;
}
__device__ __forceinline__ unsigned short f2bf(float f) {
  union { float f; unsigned int u; } v; v.f = f;
  unsigned int u = v.u;
  return (unsigned short)((u + 0x7fffu + ((u >> 16) & 1u)) >> 16);  // RNE
}
__device__ __forceinline__ uint4 pack8(float4 f0, float4 f1) {
  uint4 r;
  r.x = (unsigned)f2bf(f0.x) | ((unsigned)f2bf(f0.y) << 16);
  r.y = (unsigned)f2bf(f0.z) | ((unsigned)f2bf(f0.w) << 16);
  r.z = (unsigned)f2bf(f1.x) | ((unsigned)f2bf(f1.y) << 16);
  r.w = (unsigned)f2bf(f1.z) | ((unsigned)f2bf(f1.w) << 16);
  return r;
}

// ---------------- prep: convert X->bf16 + score GEMV; convert W->bf16 ----------------
// blocks 0..2047: X rows (4 rows/block, 1 row/wave) + score
// blocks 2048..2175: W rows (4 rows/block)
__global__ __launch_bounds__(256) void prep_kern(
    const float* __restrict__ X, const float* __restrict__ Wf,
    const float* __restrict__ Sw, const float* __restrict__ Sb,
    unsigned short* __restrict__ Xb, unsigned short* __restrict__ Wb,
    float* __restrict__ S)
{
  const int lane = threadIdx.x & 63;
  const int wave = threadIdx.x >> 6;
  const int bid  = blockIdx.x;
  if (bid < M_ROWS / 4) {
    const int m = bid * 4 + wave;
    const float* xf = X + (size_t)m * Cc + lane * 8;
    const float4 x0 = *(const float4*)xf, x1 = *(const float4*)(xf + 4);
    *(uint4*)(Xb + (size_t)m * Cc + lane * 8) = pack8(x0, x1);
    const float* wf = Sw + lane * 8;
    const float4 w0 = *(const float4*)wf, w1 = *(const float4*)(wf + 4);
    float s = x0.x * w0.x + x0.y * w0.y + x0.z * w0.z + x0.w * w0.w
            + x1.x * w1.x + x1.y * w1.y + x1.z * w1.z + x1.w * w1.w;
    #pragma unroll
    for (int off = 32; off > 0; off >>= 1) s += __shfl_down(s, off, 64);
    if (lane == 0) S[m] = s + Sb[0];
  } else {
    const int r = (bid - M_ROWS / 4) * 4 + wave;
    const float* wf = Wf + (size_t)r * Cc + lane * 8;
    const float4 f0 = *(const float4*)wf, f1 = *(const float4*)(wf + 4);
    *(uint4*)(Wb + (size_t)r * Cc + lane * 8) = pack8(f0, f1);
  }
}

// ---------------- GEMM: P[m,o] = bf16( sum_c Xb[m,c]*Wb[o,c] + bias[o] ) ----------------
#define BM 128
#define BN 64
#define BK 32

__global__ __launch_bounds__(256) void gemm_proj(
    const bf16_t* __restrict__ Xb, const bf16_t* __restrict__ Wb,
    const float* __restrict__ Bp, unsigned short* __restrict__ P)
{
  __shared__ bf16_t lA[BM * BK];   // 8 KiB
  __shared__ bf16_t lB[BN * BK];   // 4 KiB
  const int t    = threadIdx.x;
  const int bm   = blockIdx.x;   // 0..63
  const int bn   = blockIdx.y;   // 0..7
  const int lane = t & 63;
  const int wave = t >> 6;
  const int wm   = (wave >> 1) * 64;
  const int wn   = (wave & 1) * 32;

  f32x4 acc[4][2];
  #pragma unroll
  for (int a = 0; a < 4; a++)
    #pragma unroll
    for (int b = 0; b < 2; b++) acc[a][b] = (f32x4){0.f, 0.f, 0.f, 0.f};

  const int r0 = t >> 2;
  const int c0 = (t & 3) * 8;
  const bf16_t* Ag = Xb + (size_t)(bm * BM + r0) * Cc + c0;
  const bf16_t* Bg = Wb + (size_t)(bn * BN + r0) * Cc + c0;

  for (int k0 = 0; k0 < Cc; k0 += BK) {
    __syncthreads();
    __builtin_amdgcn_global_load_lds((const GAS void*)(Ag + k0),           (LAS void*)&lA[t * 8],         16, 0, 0);
    __builtin_amdgcn_global_load_lds((const GAS void*)(Ag + 64 * Cc + k0), (LAS void*)&lA[(t + 256) * 8], 16, 0, 0);
    __builtin_amdgcn_global_load_lds((const GAS void*)(Bg + k0),           (LAS void*)&lB[t * 8],         16, 0, 0);
    __syncthreads();

    const int kof = (lane >> 4) * 8;
    bf16x8 af[4], bfr[2];
    #pragma unroll
    for (int mt = 0; mt < 4; mt++)
      af[mt] = *(const bf16x8*)&lA[(wm + mt * 16 + (lane & 15)) * BK + kof];
    #pragma unroll
    for (int nt = 0; nt < 2; nt++)
      bfr[nt] = *(const bf16x8*)&lB[(wn + nt * 16 + (lane & 15)) * BK + kof];
    #pragma unroll
    for (int mt = 0; mt < 4; mt++)
      #pragma unroll
      for (int nt = 0; nt < 2; nt++)
        acc[mt][nt] = __builtin_amdgcn_mfma_f32_16x16x32_bf16(af[mt], bfr[nt], acc[mt][nt], 0, 0, 0);
  }

  // epilogue: C/D layout col=lane&15 (o), row=(lane>>4)*4+r (m)
  #pragma unroll
  for (int nt = 0; nt < 2; nt++) {
    const int col = bn * BN + wn + nt * 16 + (lane & 15);
    const float bias = Bp[col];
    #pragma unroll
    for (int mt = 0; mt < 4; mt++) {
      #pragma unroll
      for (int r = 0; r < 4; r++) {
        const int row = bm * BM + wm + mt * 16 + (lane >> 4) * 4 + r;
        P[(size_t)row * Oo + col] = f2bf(acc[mt][nt][r] + bias);
      }
    }
  }
}

// ---------------- combine: LN(25 scores) -> softmax -> weighted sum ----------------
// block = (i, n), 512 threads: thread -> (8-ch group, 4-j group)
__global__ __launch_bounds__(512) void combine_kern(
    const unsigned short* __restrict__ P, const float* __restrict__ S,
    const float* __restrict__ lnw, const float* __restrict__ lnb,
    float* __restrict__ out)
{
  const int i = blockIdx.x;   // 0..27
  const int n = blockIdx.y;   // 0..7
  const int t = threadIdx.x;

  __shared__ float sc[5][32];   // score rows i..i+4, all 32 cols
  __shared__ float lw[28][25];  // softmax weights per output col j

  if (t < 160) sc[t >> 5][t & 31] = S[(n * Hi + i + (t >> 5)) * Wi + (t & 31)];
  __syncthreads();

  if (t < 28) {
    const int j = t;
    float mu = 0.f;
    #pragma unroll
    for (int q = 0; q < 25; q++) mu += sc[q / 5][j + q % 5];
    mu *= (1.0f / 25.0f);
    float var = 0.f;
    #pragma unroll
    for (int q = 0; q < 25; q++) { const float d = sc[q / 5][j + q % 5] - mu; var += d * d; }
    var *= (1.0f / 25.0f);
    const float rr = rsqrtf(var + 1e-5f);
    float e[25], mx = -1e30f;
    #pragma unroll
    for (int q = 0; q < 25; q++) {
      e[q] = (sc[q / 5][j + q % 5] - mu) * rr * lnw[q] + lnb[q];
      mx = fmaxf(mx, e[q]);
    }
    float den = 0.f;
    #pragma unroll
    for (int q = 0; q < 25; q++) { e[q] = __expf(e[q] - mx); den += e[q]; }
    const float inv = 1.0f / den;
    #pragma unroll
    for (int q = 0; q < 25; q++) lw[j][q] = e[q] * inv;
  }
  __syncthreads();

  const int chg = t & 63;       // 8-channel group: ch = chg*8..chg*8+7
  const int jq  = t >> 6;       // 0..7; jq<7 handles j = jq*4..jq*4+3
  if (jq >= 7) return;
  const int c0 = jq * 4;

  float acc[4][8];
  #pragma unroll
  for (int a = 0; a < 4; a++)
    #pragma unroll
    for (int b = 0; b < 8; b++) acc[a][b] = 0.f;

  const unsigned short* Pb = P + chg * 8;
  #pragma unroll
  for (int col = 0; col < 8; col++) {
    const int c = c0 + col;
    float f[5][8];
    #pragma unroll
    for (int ki = 0; ki < 5; ki++) {
      const uint4 v = *(const uint4*)(Pb + (size_t)((n * Hi + i + ki) * Wi + c) * Oo);
      f[ki][0] = bf2f((unsigned short)(v.x & 0xFFFFu)); f[ki][1] = bf2f((unsigned short)(v.x >> 16));
      f[ki][2] = bf2f((unsigned short)(v.y & 0xFFFFu)); f[ki][3] = bf2f((unsigned short)(v.y >> 16));
      f[ki][4] = bf2f((unsigned short)(v.z & 0xFFFFu)); f[ki][5] = bf2f((unsigned short)(v.z >> 16));
      f[ki][6] = bf2f((unsigned short)(v.w & 0xFFFFu)); f[ki][7] = bf2f((unsigned short)(v.w >> 16));
    }
    #pragma unroll
    for (int jj = 0; jj < 4; jj++) {
      const int kj = col - jj;
      if (kj >= 0 && kj < 5) {
        #pragma unroll
        for (int ki = 0; ki < 5; ki++) {
          const float w_ = lw[c0 + jj][ki * 5 + kj];
          #pragma unroll
          for (int ch = 0; ch < 8; ch++) acc[jj][ch] += f[ki][ch] * w_;
        }
      }
    }
  }

  // out[..., i, c0+jj] contiguous in jj -> float4 store per channel
  #pragma unroll
  for (int ch = 0; ch < 8; ch++) {
    float4 q;
    q.x = acc[0][ch]; q.y = acc[1][ch]; q.z = acc[2][ch]; q.w = acc[3][ch];
    *(float4*)&out[(((size_t)n * Oo + chg * 8 + ch) * HO + i) * WO + c0] = q;
  }
}

extern "C" void kernel_launch(void* const* d_in, const int* in_sizes, int n_in,
                              void* d_out, int out_size, void* d_ws, size_t ws_size,
                              hipStream_t stream) {
  const float* x   = (const float*)d_in[0];
  const float* pw  = (const float*)d_in[1];
  const float* pb  = (const float*)d_in[2];
  const float* sw  = (const float*)d_in[3];
  const float* sb  = (const float*)d_in[4];
  const float* lnw = (const float*)d_in[5];
  const float* lnb = (const float*)d_in[6];

  char* w = (char*)d_ws;
  float*          Sv = (float*)w;                                   // 32 KiB
  unsigned short* Xb = (unsigned short*)(w + 64 * 1024);            // 8 MiB
  unsigned short* Wb = (unsigned short*)(w + 64 * 1024 + (size_t)M_ROWS * Cc * 2);  // 512 KiB
  unsigned short* P  = (unsigned short*)(w + 64 * 1024 + (size_t)M_ROWS * Cc * 2 + (size_t)Oo * Cc * 2);  // 8 MiB

  prep_kern<<<dim3(M_ROWS / 4 + Oo / 4), 256, 0, stream>>>(x, pw, sw, sb, Xb, Wb, Sv);
  gemm_proj<<<dim3(M_ROWS / BM, Oo / BN), 256, 0, stream>>>((const bf16_t*)Xb, (const bf16_t*)Wb, pb, P);
  combine_kern<<<dim3(HO, Nn), 512, 0, stream>>>(P, Sv, lnw, lnb, (float*)d_out);
}

// Round 6
// 112.006 us; speedup vs baseline: 1.2962x; 1.2962x over previous
//
#include <hip/hip_runtime.h>

typedef __bf16 bf16_t;
typedef bf16_t bf16x8 __attribute__((ext_vector_type(8)));
typedef float  f32x4  __attribute__((ext_vector_type(4)));

#define GAS __attribute__((address_space(1)))
#define LAS __attribute__((address_space(3)))

static constexpr int Nn = 8, Cc = 512, Hi = 32, Wi = 32, Oo = 512;
static constexpr int HO = 28, WO = 28;
static constexpr int NPOS = HO * WO;         // 784
static constexpr int M_ROWS = Nn * Hi * Wi;  // 8192

__device__ __forceinline__ float bf2f(unsigned short u) {
  union { unsigned int i; float f; } v; v.i = ((unsigned int)u) << 16; return v.f;
}
__device__ __forceinline__ unsigned short f2bf(float f) {
  union { float f; unsigned int u; } v; v.f = f;
  unsigned int u = v.u;
  return (unsigned short)((u + 0x7fffu + ((u >> 16) & 1u)) >> 16);  // RNE
}
__device__ __forceinline__ uint4 pack8(float4 f0, float4 f1) {
  uint4 r;
  r.x = (unsigned)f2bf(f0.x) | ((unsigned)f2bf(f0.y) << 16);
  r.y = (unsigned)f2bf(f0.z) | ((unsigned)f2bf(f0.w) << 16);
  r.z = (unsigned)f2bf(f1.x) | ((unsigned)f2bf(f1.y) << 16);
  r.w = (unsigned)f2bf(f1.z) | ((unsigned)f2bf(f1.w) << 16);
  return r;
}

// ---------------- prep: convert X->bf16 + score GEMV; convert W->bf16 ----------------
__global__ __launch_bounds__(256) void prep_kern(
    const float* __restrict__ X, const float* __restrict__ Wf,
    const float* __restrict__ Sw, const float* __restrict__ Sb,
    unsigned short* __restrict__ Xb, unsigned short* __restrict__ Wb,
    float* __restrict__ S)
{
  const int lane = threadIdx.x & 63;
  const int wave = threadIdx.x >> 6;
  const int bid  = blockIdx.x;
  if (bid < M_ROWS / 4) {
    const int m = bid * 4 + wave;
    const float* xf = X + (size_t)m * Cc + lane * 8;
    const float4 x0 = *(const float4*)xf, x1 = *(const float4*)(xf + 4);
    *(uint4*)(Xb + (size_t)m * Cc + lane * 8) = pack8(x0, x1);
    const float* wf = Sw + lane * 8;
    const float4 w0 = *(const float4*)wf, w1 = *(const float4*)(wf + 4);
    float s = x0.x * w0.x + x0.y * w0.y + x0.z * w0.z + x0.w * w0.w
            + x1.x * w1.x + x1.y * w1.y + x1.z * w1.z + x1.w * w1.w;
    #pragma unroll
    for (int off = 32; off > 0; off >>= 1) s += __shfl_down(s, off, 64);
    if (lane == 0) S[m] = s + Sb[0];
  } else {
    const int r = (bid - M_ROWS / 4) * 4 + wave;
    const float* wf = Wf + (size_t)r * Cc + lane * 8;
    const float4 f0 = *(const float4*)wf, f1 = *(const float4*)(wf + 4);
    *(uint4*)(Wb + (size_t)r * Cc + lane * 8) = pack8(f0, f1);
  }
}

// ---------------- wattn: LN(25 scores) + softmax -> Wat[n][pos][28pad] ----------------
__global__ __launch_bounds__(256) void wattn_kern(
    const float* __restrict__ S, const float* __restrict__ lnw,
    const float* __restrict__ lnb, float* __restrict__ Wat)
{
  const int n = blockIdx.x;
  const int t = threadIdx.x;
  __shared__ float sl[Hi * Wi];
  __shared__ float lw[25], lb[25];
  #pragma unroll
  for (int k = 0; k < 4; k++) sl[k * 256 + t] = S[n * Hi * Wi + k * 256 + t];
  if (t < 25) { lw[t] = lnw[t]; lb[t] = lnb[t]; }
  __syncthreads();

  #pragma unroll
  for (int k = 0; k < 4; k++) {
    const int pos = k * 256 + t;
    if (pos < NPOS) {
      const int i = pos / WO;
      const int j = pos - i * WO;
      float v[25], mu = 0.f;
      #pragma unroll
      for (int q = 0; q < 25; q++) { v[q] = sl[(i + q / 5) * Wi + j + q % 5]; mu += v[q]; }
      mu *= (1.0f / 25.0f);
      float var = 0.f;
      #pragma unroll
      for (int q = 0; q < 25; q++) { const float d = v[q] - mu; var += d * d; }
      var *= (1.0f / 25.0f);
      const float rr = rsqrtf(var + 1e-5f);
      float mx = -1e30f;
      #pragma unroll
      for (int q = 0; q < 25; q++) { v[q] = (v[q] - mu) * rr * lw[q] + lb[q]; mx = fmaxf(mx, v[q]); }
      float den = 0.f;
      #pragma unroll
      for (int q = 0; q < 25; q++) { v[q] = __expf(v[q] - mx); den += v[q]; }
      const float inv = 1.0f / den;
      float* wp = Wat + ((size_t)n * NPOS + pos) * 28;
      #pragma unroll
      for (int q = 0; q < 25; q++) wp[q] = v[q] * inv;
    }
  }
}

// ---------------- GEMM: P[m,o] = bf16( sum_c Xb[m,c]*Wb[o,c] + bias[o] ) ----------------
#define BM 128
#define BN 64
#define BK 32

__global__ __launch_bounds__(256) void gemm_proj(
    const bf16_t* __restrict__ Xb, const bf16_t* __restrict__ Wb,
    const float* __restrict__ Bp, unsigned short* __restrict__ P)
{
  __shared__ bf16_t lA[BM * BK];   // 8 KiB
  __shared__ bf16_t lB[BN * BK];   // 4 KiB
  const int t    = threadIdx.x;
  const int bm   = blockIdx.x;
  const int bn   = blockIdx.y;
  const int lane = t & 63;
  const int wave = t >> 6;
  const int wm   = (wave >> 1) * 64;
  const int wn   = (wave & 1) * 32;

  f32x4 acc[4][2];
  #pragma unroll
  for (int a = 0; a < 4; a++)
    #pragma unroll
    for (int b = 0; b < 2; b++) acc[a][b] = (f32x4){0.f, 0.f, 0.f, 0.f};

  const int r0 = t >> 2;
  const int c0 = (t & 3) * 8;
  const bf16_t* Ag = Xb + (size_t)(bm * BM + r0) * Cc + c0;
  const bf16_t* Bg = Wb + (size_t)(bn * BN + r0) * Cc + c0;

  for (int k0 = 0; k0 < Cc; k0 += BK) {
    __syncthreads();
    __builtin_amdgcn_global_load_lds((const GAS void*)(Ag + k0),           (LAS void*)&lA[t * 8],         16, 0, 0);
    __builtin_amdgcn_global_load_lds((const GAS void*)(Ag + 64 * Cc + k0), (LAS void*)&lA[(t + 256) * 8], 16, 0, 0);
    __builtin_amdgcn_global_load_lds((const GAS void*)(Bg + k0),           (LAS void*)&lB[t * 8],         16, 0, 0);
    __syncthreads();

    const int kof = (lane >> 4) * 8;
    bf16x8 af[4], bfr[2];
    #pragma unroll
    for (int mt = 0; mt < 4; mt++)
      af[mt] = *(const bf16x8*)&lA[(wm + mt * 16 + (lane & 15)) * BK + kof];
    #pragma unroll
    for (int nt = 0; nt < 2; nt++)
      bfr[nt] = *(const bf16x8*)&lB[(wn + nt * 16 + (lane & 15)) * BK + kof];
    #pragma unroll
    for (int mt = 0; mt < 4; mt++)
      #pragma unroll
      for (int nt = 0; nt < 2; nt++)
        acc[mt][nt] = __builtin_amdgcn_mfma_f32_16x16x32_bf16(af[mt], bfr[nt], acc[mt][nt], 0, 0, 0);
  }

  #pragma unroll
  for (int nt = 0; nt < 2; nt++) {
    const int col = bn * BN + wn + nt * 16 + (lane & 15);
    const float bias = Bp[col];
    #pragma unroll
    for (int mt = 0; mt < 4; mt++) {
      #pragma unroll
      for (int r = 0; r < 4; r++) {
        const int row = bm * BM + wm + mt * 16 + (lane >> 4) * 4 + r;
        P[(size_t)row * Oo + col] = f2bf(acc[mt][nt][r] + bias);
      }
    }
  }
}

// ---------------- combine: block = (16-ch group, n); coalesced writes ----------------
__global__ __launch_bounds__(256) void combine_kern(
    const unsigned short* __restrict__ P, const float* __restrict__ Wat,
    float* __restrict__ out)
{
  const int g = blockIdx.x;   // 0..31
  const int n = blockIdx.y;   // 0..7
  const int t = threadIdx.x;
  const int ch0 = g * 16;

  __shared__ unsigned short Pt[Hi * Wi * 16];  // [row=hi*32+wi][16 ch] = 32 KiB

  // stage 2048 16-B chunks; LDS dest is lane-linear -> global_load_lds OK
  const unsigned short* Pg = P + (size_t)n * Hi * Wi * Oo + ch0;
  #pragma unroll
  for (int itr = 0; itr < 8; itr++) {
    const int id = itr * 256 + t;
    const int row = id >> 1, half = id & 1;
    __builtin_amdgcn_global_load_lds((const GAS void*)(Pg + row * Oo + half * 8),
                                     (LAS void*)&Pt[id * 8], 16, 0, 0);
  }
  __syncthreads();

  for (int itp = 0; itp < 4; itp++) {
    const int pos = itp * 256 + t;
    if (pos < NPOS) {
      const int i = pos / WO;
      const int j = pos - i * WO;
      const float* wp = Wat + ((size_t)n * NPOS + pos) * 28;
      const float4 w0 = *(const float4*)(wp);
      const float4 w1 = *(const float4*)(wp + 4);
      const float4 w2 = *(const float4*)(wp + 8);
      const float4 w3 = *(const float4*)(wp + 12);
      const float4 w4 = *(const float4*)(wp + 16);
      const float4 w5 = *(const float4*)(wp + 20);
      const float4 w6 = *(const float4*)(wp + 24);
      const float wq[25] = {w0.x,w0.y,w0.z,w0.w, w1.x,w1.y,w1.z,w1.w,
                            w2.x,w2.y,w2.z,w2.w, w3.x,w3.y,w3.z,w3.w,
                            w4.x,w4.y,w4.z,w4.w, w5.x,w5.y,w5.z,w5.w, w6.x};
      float acc[16];
      #pragma unroll
      for (int c = 0; c < 16; c++) acc[c] = 0.f;
      #pragma unroll
      for (int ki = 0; ki < 5; ki++) {
        const int rb = (i + ki) * Wi + j;
        #pragma unroll
        for (int kj = 0; kj < 5; kj++) {
          const uint4* pr = (const uint4*)&Pt[(rb + kj) * 16];
          const uint4 a = pr[0], b = pr[1];
          const float wv = wq[ki * 5 + kj];
          acc[0]  += bf2f((unsigned short)(a.x & 0xFFFFu)) * wv;
          acc[1]  += bf2f((unsigned short)(a.x >> 16)) * wv;
          acc[2]  += bf2f((unsigned short)(a.y & 0xFFFFu)) * wv;
          acc[3]  += bf2f((unsigned short)(a.y >> 16)) * wv;
          acc[4]  += bf2f((unsigned short)(a.z & 0xFFFFu)) * wv;
          acc[5]  += bf2f((unsigned short)(a.z >> 16)) * wv;
          acc[6]  += bf2f((unsigned short)(a.w & 0xFFFFu)) * wv;
          acc[7]  += bf2f((unsigned short)(a.w >> 16)) * wv;
          acc[8]  += bf2f((unsigned short)(b.x & 0xFFFFu)) * wv;
          acc[9]  += bf2f((unsigned short)(b.x >> 16)) * wv;
          acc[10] += bf2f((unsigned short)(b.y & 0xFFFFu)) * wv;
          acc[11] += bf2f((unsigned short)(b.y >> 16)) * wv;
          acc[12] += bf2f((unsigned short)(b.z & 0xFFFFu)) * wv;
          acc[13] += bf2f((unsigned short)(b.z >> 16)) * wv;
          acc[14] += bf2f((unsigned short)(b.w & 0xFFFFu)) * wv;
          acc[15] += bf2f((unsigned short)(b.w >> 16)) * wv;
        }
      }
      // lanes = consecutive pos -> contiguous 256-B segments per channel store
      float* og = out + ((size_t)n * Oo + ch0) * NPOS + pos;
      #pragma unroll
      for (int c = 0; c < 16; c++) og[(size_t)c * NPOS] = acc[c];
    }
  }
}

extern "C" void kernel_launch(void* const* d_in, const int* in_sizes, int n_in,
                              void* d_out, int out_size, void* d_ws, size_t ws_size,
                              hipStream_t stream) {
  const float* x   = (const float*)d_in[0];
  const float* pw  = (const float*)d_in[1];
  const float* pb  = (const float*)d_in[2];
  const float* sw  = (const float*)d_in[3];
  const float* sb  = (const float*)d_in[4];
  const float* lnw = (const float*)d_in[5];
  const float* lnb = (const float*)d_in[6];

  char* w = (char*)d_ws;
  float*          Sv  = (float*)w;                                        // 32 KiB
  unsigned short* Xb  = (unsigned short*)(w + (64 << 10));                // 8 MiB
  unsigned short* Wb  = (unsigned short*)(w + (64 << 10) + (8 << 20));    // 512 KiB
  unsigned short* P   = (unsigned short*)(w + (64 << 10) + (8 << 20) + (512 << 10));  // 8 MiB
  float*          Wat = (float*)(w + (64 << 10) + (16 << 20) + (512 << 10));          // 702 KiB

  prep_kern<<<dim3(M_ROWS / 4 + Oo / 4), 256, 0, stream>>>(x, pw, sw, sb, Xb, Wb, Sv);
  wattn_kern<<<dim3(Nn), 256, 0, stream>>>(Sv, lnw, lnb, Wat);
  gemm_proj<<<dim3(M_ROWS / BM, Oo / BN), 256, 0, stream>>>((const bf16_t*)Xb, (const bf16_t*)Wb, pb, P);
  combine_kern<<<dim3(Oo / 16, Nn), 256, 0, stream>>>(P, Wat, (float*)d_out);
}

// Round 7
// 108.973 us; speedup vs baseline: 1.3323x; 1.0278x over previous
//
#include <hip/hip_runtime.h>

typedef __bf16 bf16_t;
typedef bf16_t bf16x8 __attribute__((ext_vector_type(8)));
typedef float  f32x4  __attribute__((ext_vector_type(4)));

#define GAS __attribute__((address_space(1)))
#define LAS __attribute__((address_space(3)))

static constexpr int Nn = 8, Cc = 512, Hi = 32, Wi = 32, Oo = 512;
static constexpr int HO = 28, WO = 28;
static constexpr int NPOS = HO * WO;         // 784
static constexpr int M_ROWS = Nn * Hi * Wi;  // 8192

__device__ __forceinline__ float bf2f(unsigned short u) {
  union { unsigned int i; float f; } v; v.i = ((unsigned int)u) << 16; return v.f;
}
__device__ __forceinline__ unsigned short f2bf(float f) {
  union { float f; unsigned int u; } v; v.f = f;
  unsigned int u = v.u;
  return (unsigned short)((u + 0x7fffu + ((u >> 16) & 1u)) >> 16);  // RNE
}
__device__ __forceinline__ uint4 pack8(float4 f0, float4 f1) {
  uint4 r;
  r.x = (unsigned)f2bf(f0.x) | ((unsigned)f2bf(f0.y) << 16);
  r.y = (unsigned)f2bf(f0.z) | ((unsigned)f2bf(f0.w) << 16);
  r.z = (unsigned)f2bf(f1.x) | ((unsigned)f2bf(f1.y) << 16);
  r.w = (unsigned)f2bf(f1.z) | ((unsigned)f2bf(f1.w) << 16);
  return r;
}

// ---------------- prep: convert X->bf16 + score GEMV; convert W->bf16 ----------------
__global__ __launch_bounds__(256) void prep_kern(
    const float* __restrict__ X, const float* __restrict__ Wf,
    const float* __restrict__ Sw, const float* __restrict__ Sb,
    unsigned short* __restrict__ Xb, unsigned short* __restrict__ Wb,
    float* __restrict__ S)
{
  const int lane = threadIdx.x & 63;
  const int wave = threadIdx.x >> 6;
  const int bid  = blockIdx.x;
  if (bid < M_ROWS / 4) {
    const int m = bid * 4 + wave;
    const float* xf = X + (size_t)m * Cc + lane * 8;
    const float4 x0 = *(const float4*)xf, x1 = *(const float4*)(xf + 4);
    *(uint4*)(Xb + (size_t)m * Cc + lane * 8) = pack8(x0, x1);
    const float* wf = Sw + lane * 8;
    const float4 w0 = *(const float4*)wf, w1 = *(const float4*)(wf + 4);
    float s = x0.x * w0.x + x0.y * w0.y + x0.z * w0.z + x0.w * w0.w
            + x1.x * w1.x + x1.y * w1.y + x1.z * w1.z + x1.w * w1.w;
    #pragma unroll
    for (int off = 32; off > 0; off >>= 1) s += __shfl_down(s, off, 64);
    if (lane == 0) S[m] = s + Sb[0];
  } else {
    const int r = (bid - M_ROWS / 4) * 4 + wave;
    const float* wf = Wf + (size_t)r * Cc + lane * 8;
    const float4 f0 = *(const float4*)wf, f1 = *(const float4*)(wf + 4);
    *(uint4*)(Wb + (size_t)r * Cc + lane * 8) = pack8(f0, f1);
  }
}

// ---------------- GEMM: P[m,o] = bf16( sum_c Xb[m,c]*Wb[o,c] + bias[o] ) ----------------
#define BM 128
#define BN 64
#define BK 32

__global__ __launch_bounds__(256) void gemm_proj(
    const bf16_t* __restrict__ Xb, const bf16_t* __restrict__ Wb,
    const float* __restrict__ Bp, unsigned short* __restrict__ P)
{
  __shared__ bf16_t lA[BM * BK];   // 8 KiB
  __shared__ bf16_t lB[BN * BK];   // 4 KiB
  const int t    = threadIdx.x;
  const int bm   = blockIdx.x;
  const int bn   = blockIdx.y;
  const int lane = t & 63;
  const int wave = t >> 6;
  const int wm   = (wave >> 1) * 64;
  const int wn   = (wave & 1) * 32;

  f32x4 acc[4][2];
  #pragma unroll
  for (int a = 0; a < 4; a++)
    #pragma unroll
    for (int b = 0; b < 2; b++) acc[a][b] = (f32x4){0.f, 0.f, 0.f, 0.f};

  const int r0 = t >> 2;
  const int c0 = (t & 3) * 8;
  const bf16_t* Ag = Xb + (size_t)(bm * BM + r0) * Cc + c0;
  const bf16_t* Bg = Wb + (size_t)(bn * BN + r0) * Cc + c0;

  for (int k0 = 0; k0 < Cc; k0 += BK) {
    __syncthreads();
    __builtin_amdgcn_global_load_lds((const GAS void*)(Ag + k0),           (LAS void*)&lA[t * 8],         16, 0, 0);
    __builtin_amdgcn_global_load_lds((const GAS void*)(Ag + 64 * Cc + k0), (LAS void*)&lA[(t + 256) * 8], 16, 0, 0);
    __builtin_amdgcn_global_load_lds((const GAS void*)(Bg + k0),           (LAS void*)&lB[t * 8],         16, 0, 0);
    __syncthreads();

    const int kof = (lane >> 4) * 8;
    bf16x8 af[4], bfr[2];
    #pragma unroll
    for (int mt = 0; mt < 4; mt++)
      af[mt] = *(const bf16x8*)&lA[(wm + mt * 16 + (lane & 15)) * BK + kof];
    #pragma unroll
    for (int nt = 0; nt < 2; nt++)
      bfr[nt] = *(const bf16x8*)&lB[(wn + nt * 16 + (lane & 15)) * BK + kof];
    #pragma unroll
    for (int mt = 0; mt < 4; mt++)
      #pragma unroll
      for (int nt = 0; nt < 2; nt++)
        acc[mt][nt] = __builtin_amdgcn_mfma_f32_16x16x32_bf16(af[mt], bfr[nt], acc[mt][nt], 0, 0, 0);
  }

  #pragma unroll
  for (int nt = 0; nt < 2; nt++) {
    const int col = bn * BN + wn + nt * 16 + (lane & 15);
    const float bias = Bp[col];
    #pragma unroll
    for (int mt = 0; mt < 4; mt++) {
      #pragma unroll
      for (int r = 0; r < 4; r++) {
        const int row = bm * BM + wm + mt * 16 + (lane >> 4) * 4 + r;
        P[(size_t)row * Oo + col] = f2bf(acc[mt][nt][r] + bias);
      }
    }
  }
}

// ---------------- combine: block = (16-ch group, n); fused LN+softmax; coalesced writes ----------------
__global__ __launch_bounds__(256) void combine_kern(
    const unsigned short* __restrict__ P, const float* __restrict__ S,
    const float* __restrict__ lnw, const float* __restrict__ lnb,
    float* __restrict__ out)
{
  const int g = blockIdx.x;   // 0..31
  const int n = blockIdx.y;   // 0..7
  const int t = threadIdx.x;
  const int ch0 = g * 16;

  __shared__ unsigned short Pt[Hi * Wi * 16];  // 32 KiB: [row=hi*32+wi][16 ch]
  __shared__ float sl[Hi * Wi];                // 4 KiB: score plane
  __shared__ float lwv[25], lbv[25];

  // stage P tile: 2048 16-B chunks, lane-linear dest -> global_load_lds OK
  const unsigned short* Pg = P + (size_t)n * Hi * Wi * Oo + ch0;
  #pragma unroll
  for (int itr = 0; itr < 8; itr++) {
    const int id = itr * 256 + t;
    const int row = id >> 1, half = id & 1;
    __builtin_amdgcn_global_load_lds((const GAS void*)(Pg + row * Oo + half * 8),
                                     (LAS void*)&Pt[id * 8], 16, 0, 0);
  }
  #pragma unroll
  for (int k = 0; k < 4; k++) sl[k * 256 + t] = S[n * Hi * Wi + k * 256 + t];
  if (t < 25) { lwv[t] = lnw[t]; lbv[t] = lnb[t]; }
  __syncthreads();

  for (int itp = 0; itp < 4; itp++) {
    const int pos = itp * 256 + t;
    if (pos < NPOS) {
      const int i = pos / WO;
      const int j = pos - i * WO;

      // LN over the 5x5 score window + softmax -> 25 weights in registers
      float v[25], mu = 0.f;
      #pragma unroll
      for (int q = 0; q < 25; q++) { v[q] = sl[(i + q / 5) * Wi + j + q % 5]; mu += v[q]; }
      mu *= (1.0f / 25.0f);
      float var = 0.f;
      #pragma unroll
      for (int q = 0; q < 25; q++) { const float d = v[q] - mu; var += d * d; }
      var *= (1.0f / 25.0f);
      const float rr = rsqrtf(var + 1e-5f);
      float mx = -1e30f;
      #pragma unroll
      for (int q = 0; q < 25; q++) { v[q] = (v[q] - mu) * rr * lwv[q] + lbv[q]; mx = fmaxf(mx, v[q]); }
      float den = 0.f;
      #pragma unroll
      for (int q = 0; q < 25; q++) { v[q] = __expf(v[q] - mx); den += v[q]; }
      const float inv = 1.0f / den;
      #pragma unroll
      for (int q = 0; q < 25; q++) v[q] *= inv;

      float acc[16];
      #pragma unroll
      for (int c = 0; c < 16; c++) acc[c] = 0.f;
      #pragma unroll
      for (int ki = 0; ki < 5; ki++) {
        const int rb = (i + ki) * Wi + j;
        #pragma unroll
        for (int kj = 0; kj < 5; kj++) {
          const uint4* pr = (const uint4*)&Pt[(rb + kj) * 16];
          const uint4 a = pr[0], b = pr[1];
          const float wv = v[ki * 5 + kj];
          acc[0]  += bf2f((unsigned short)(a.x & 0xFFFFu)) * wv;
          acc[1]  += bf2f((unsigned short)(a.x >> 16)) * wv;
          acc[2]  += bf2f((unsigned short)(a.y & 0xFFFFu)) * wv;
          acc[3]  += bf2f((unsigned short)(a.y >> 16)) * wv;
          acc[4]  += bf2f((unsigned short)(a.z & 0xFFFFu)) * wv;
          acc[5]  += bf2f((unsigned short)(a.z >> 16)) * wv;
          acc[6]  += bf2f((unsigned short)(a.w & 0xFFFFu)) * wv;
          acc[7]  += bf2f((unsigned short)(a.w >> 16)) * wv;
          acc[8]  += bf2f((unsigned short)(b.x & 0xFFFFu)) * wv;
          acc[9]  += bf2f((unsigned short)(b.x >> 16)) * wv;
          acc[10] += bf2f((unsigned short)(b.y & 0xFFFFu)) * wv;
          acc[11] += bf2f((unsigned short)(b.y >> 16)) * wv;
          acc[12] += bf2f((unsigned short)(b.z & 0xFFFFu)) * wv;
          acc[13] += bf2f((unsigned short)(b.z >> 16)) * wv;
          acc[14] += bf2f((unsigned short)(b.w & 0xFFFFu)) * wv;
          acc[15] += bf2f((unsigned short)(b.w >> 16)) * wv;
        }
      }
      // lanes = consecutive pos -> contiguous 256-B segments per channel store
      float* og = out + ((size_t)n * Oo + ch0) * NPOS + pos;
      #pragma unroll
      for (int c = 0; c < 16; c++) og[(size_t)c * NPOS] = acc[c];
    }
  }
}

extern "C" void kernel_launch(void* const* d_in, const int* in_sizes, int n_in,
                              void* d_out, int out_size, void* d_ws, size_t ws_size,
                              hipStream_t stream) {
  const float* x   = (const float*)d_in[0];
  const float* pw  = (const float*)d_in[1];
  const float* pb  = (const float*)d_in[2];
  const float* sw  = (const float*)d_in[3];
  const float* sb  = (const float*)d_in[4];
  const float* lnw = (const float*)d_in[5];
  const float* lnb = (const float*)d_in[6];

  char* w = (char*)d_ws;
  float*          Sv = (float*)w;                                        // 32 KiB
  unsigned short* Xb = (unsigned short*)(w + (64 << 10));                // 8 MiB
  unsigned short* Wb = (unsigned short*)(w + (64 << 10) + (8 << 20));    // 512 KiB
  unsigned short* P  = (unsigned short*)(w + (64 << 10) + (8 << 20) + (512 << 10));  // 8 MiB

  prep_kern<<<dim3(M_ROWS / 4 + Oo / 4), 256, 0, stream>>>(x, pw, sw, sb, Xb, Wb, Sv);
  gemm_proj<<<dim3(M_ROWS / BM, Oo / BN), 256, 0, stream>>>((const bf16_t*)Xb, (const bf16_t*)Wb, pb, P);
  combine_kern<<<dim3(Oo / 16, Nn), 256, 0, stream>>>(P, Sv, lnw, lnb, (float*)d_out);
}